// Round 9
// baseline (2770.629 us; speedup 1.0000x reference)
//
#include <hip/hip_runtime.h>

#define T_STEPS 4096
#define BATCH   64
#define INDIM   4
#define H       256
#define OUTD    2
#define CHUNK   32
// h entry: 8 k-segments (32 f16 = 64 B each) at 80-B stride -> segment s
// starts at dword 20s: banks (20s)%32 = {0,20,8,28,16,4,24,12} — disjoint
// bank-quads for the 8 broadcast address-groups of a wave.
#define SEG_DW  20
#define ENT_DW  (8*SEG_DW)            // 160 dwords = 640 B per stored h vector
#define ENT_B   (4*ENT_DW)
#define RING_DW (CHUNK*ENT_DW)        // 5120 dwords (20 KB)
#define RING_B  (4*RING_DW)
#define DUMP_DW 256                   // 1 KB dump for non-writer lanes

typedef __fp16 half2v __attribute__((ext_vector_type(2)));

__device__ __forceinline__ float fast_tanh(float x) {
    float ax = fabsf(x);
    float e  = __expf(-2.0f * ax);
    float r  = (1.0f - e) * __builtin_amdgcn_rcpf(1.0f + e);
    return copysignf(r, x);
}

// acc += dpp_shifted(acc). Empirical convention (validated by R8 passing):
// shl-reduce lands the group sum at the LOWEST lane, shr-reduce at the HIGHEST.
template<int CTRL>
__device__ __forceinline__ float dpp_radd(float a) {
    int s = __builtin_amdgcn_update_dpp(0, __builtin_bit_cast(int, a),
                                        CTRL, 0xf, 0xf, true);
    return a + __builtin_bit_cast(float, s);
}
#define SHL1 0x101
#define SHL2 0x102
#define SHL4 0x104
#define SHR1 0x111
#define SHR2 0x112

// 512 threads = 8 waves = 2 waves/SIMD. Thread owns 4 rows x 32 k's
// (64 weight dwords — the footprint proven resident in R8, VGPR=88).
// s=8 lanes per row-group -> per-thread LDS reads halve vs R8.
__global__ __attribute__((amdgpu_waves_per_eu(2, 2))) __launch_bounds__(512)
void elman_kernel(const float* __restrict__ input,
                  const float* __restrict__ Wi,
                  const float* __restrict__ bi,
                  const float* __restrict__ Wh,
                  const float* __restrict__ bh,
                  const float* __restrict__ Wf,
                  const float* __restrict__ bf,
                  float* __restrict__ out)
{
    const int b  = blockIdx.x;
    const int t  = threadIdx.x;
    const int rg = t >> 3;        // row group 0..63 (rows 4rg..4rg+3)
    const int ks = t & 7;         // k-segment: k in [32ks, 32ks+32)
    const int jj = t & 3;         // epilogue row within group
    const int is_wr = ((t & 7) < 4);

    __shared__ unsigned int lds[RING_DW + DUMP_DW + OUTD * (H / 2)];
    unsigned int* ring  = lds;
    unsigned int* wf_pk = lds + RING_DW + DUMP_DW;

    // --- weights: 4 rows x 32 k packed f16 -> 64 dwords ---
    half2v w0[16], w1[16], w2[16], w3[16];
    {
        const float* p = Wh + (size_t)(4 * rg) * H + 32 * ks;
        #pragma unroll
        for (int j = 0; j < 8; ++j) {
            float4 a0 = *(const float4*)(p + 0 * H + 4 * j);
            float4 a1 = *(const float4*)(p + 1 * H + 4 * j);
            float4 a2 = *(const float4*)(p + 2 * H + 4 * j);
            float4 a3 = *(const float4*)(p + 3 * H + 4 * j);
            w0[2 * j] = __builtin_amdgcn_cvt_pkrtz(a0.x, a0.y);
            w0[2 * j + 1] = __builtin_amdgcn_cvt_pkrtz(a0.z, a0.w);
            w1[2 * j] = __builtin_amdgcn_cvt_pkrtz(a1.x, a1.y);
            w1[2 * j + 1] = __builtin_amdgcn_cvt_pkrtz(a1.z, a1.w);
            w2[2 * j] = __builtin_amdgcn_cvt_pkrtz(a2.x, a2.y);
            w2[2 * j + 1] = __builtin_amdgcn_cvt_pkrtz(a2.z, a2.w);
            w3[2 * j] = __builtin_amdgcn_cvt_pkrtz(a3.x, a3.y);
            w3[2 * j + 1] = __builtin_amdgcn_cvt_pkrtz(a3.z, a3.w);
        }
    }
    #pragma unroll
    for (int j = 0; j < 16; ++j) {
        float f0 = __builtin_bit_cast(float, w0[j]);
        float f1 = __builtin_bit_cast(float, w1[j]);
        float f2 = __builtin_bit_cast(float, w2[j]);
        float f3 = __builtin_bit_cast(float, w3[j]);
        asm volatile("" : "+v"(f0), "+v"(f1), "+v"(f2), "+v"(f3));
        w0[j] = __builtin_bit_cast(half2v, f0);
        w1[j] = __builtin_bit_cast(half2v, f1);
        w2[j] = __builtin_bit_cast(half2v, f2);
        w3[j] = __builtin_bit_cast(half2v, f3);
    }

    // epilogue: lane jj (of lanes 0-3 in each 8-group) finalizes row 4rg+jj
    const int  row_mine = 4 * rg + jj;
    const float4 wim    = *(const float4*)(Wi + row_mine * INDIM);
    const float  biasm  = bi[row_mine] + bh[row_mine];
    const float  bf0    = bf[0], bf1 = bf[1];
    const int    boff   = (row_mine >> 5) * (SEG_DW * 4) + (row_mine & 31) * 2;
    const int    dumpoff = RING_B + t * 2;

    if (t < OUTD * (H / 2)) {
        const int o = t >> 7, e = t & 127;
        wf_pk[t] = __builtin_bit_cast(unsigned int,
            __builtin_amdgcn_cvt_pkrtz(Wf[o * H + 2 * e], Wf[o * H + 2 * e + 1]));
    }
    if (t < ENT_DW) ring[(CHUNK - 1) * ENT_DW + t] = 0u;   // h0 = 0 (incl. pads)
    __syncthreads();

    float4 xcur = *(const float4*)(input + (size_t)b * INDIM);  // step 0
    const unsigned int rd_off = (unsigned int)(ks * SEG_DW);

    for (int chunk = 0; chunk < T_STEPS / CHUNK; ++chunk) {
        #pragma unroll 1
        for (int i = 0; i < CHUNK; ++i) {
            const int step = chunk * CHUNK + i;
            int s2 = step + 1; if (s2 >= T_STEPS) s2 = T_STEPS - 1;
            float4 xnext = *(const float4*)(input + ((size_t)s2 * BATCH + b) * INDIM);

            // my 32-k segment of h (64 B): 4 b128, banks disjoint across ks
            const unsigned int* hb =
                ring + ((i + CHUNK - 1) & (CHUNK - 1)) * ENT_DW + rd_off;
            uint4 hA = *(const uint4*)(hb + 0);
            uint4 hB = *(const uint4*)(hb + 4);
            uint4 hC = *(const uint4*)(hb + 8);
            uint4 hD = *(const uint4*)(hb + 12);
            unsigned int hw[16] = {hA.x, hA.y, hA.z, hA.w, hB.x, hB.y, hB.z, hB.w,
                                   hC.x, hC.y, hC.z, hC.w, hD.x, hD.y, hD.z, hD.w};

            float acc0 = 0.f, acc1 = 0.f, acc2 = 0.f, acc3 = 0.f;
            #pragma unroll
            for (int j = 0; j < 16; ++j) {
                half2v hv = __builtin_bit_cast(half2v, hw[j]);
                acc0 = __builtin_amdgcn_fdot2(w0[j], hv, acc0, false);
                acc1 = __builtin_amdgcn_fdot2(w1[j], hv, acc1, false);
                acc2 = __builtin_amdgcn_fdot2(w2[j], hv, acc2, false);
                acc3 = __builtin_amdgcn_fdot2(w3[j], hv, acc3, false);
            }

            // stage A: fold lanes 4-7 onto 0-3 (per 8-group)
            acc0 = dpp_radd<SHL4>(acc0);
            acc1 = dpp_radd<SHL4>(acc1);
            acc2 = dpp_radd<SHL4>(acc2);
            acc3 = dpp_radd<SHL4>(acc3);
            // stage B: acc_j -> lane j of the low quad
            acc0 = dpp_radd<SHL1>(acc0);  acc0 = dpp_radd<SHL2>(acc0);
            acc1 = dpp_radd<SHR1>(acc1);  acc1 = dpp_radd<SHL2>(acc1);
            acc2 = dpp_radd<SHL1>(acc2);  acc2 = dpp_radd<SHR2>(acc2);
            acc3 = dpp_radd<SHR1>(acc3);  acc3 = dpp_radd<SHR2>(acc3);

            // unmasked epilogue: lane jj finalizes row 4rg+jj (lanes 4-7 dump)
            float sel01 = (jj & 1) ? acc1 : acc0;
            float sel23 = (jj & 1) ? acc3 : acc2;
            float accm  = (jj & 2) ? sel23 : sel01;
            float pre   = accm + biasm +
                xcur.x * wim.x + xcur.y * wim.y + xcur.z * wim.z + xcur.w * wim.w;
            __fp16 h16 = (__fp16)fast_tanh(pre);
            int waddr  = is_wr ? (i * ENT_B + boff) : dumpoff;
            *(__fp16*)((char*)lds + waddr) = h16;

            xcur = xnext;
            __syncthreads();
        }

        // --- deferred output head: 64 tasks x 8 lanes ---
        {
            const int task = t >> 3;     // (step-in-chunk, out-idx)
            const int s    = task >> 1;
            const int o    = task & 1;
            const int sub  = t & 7;      // 32-k segment
            const unsigned int* hp = ring + s * ENT_DW + sub * SEG_DW;
            const unsigned int* wp = wf_pk + o * (H / 2) + sub * 16;

            uint4 hA = *(const uint4*)(hp);
            uint4 hB = *(const uint4*)(hp + 4);
            uint4 hC = *(const uint4*)(hp + 8);
            uint4 hD = *(const uint4*)(hp + 12);
            uint4 wA = *(const uint4*)(wp);
            uint4 wB = *(const uint4*)(wp + 4);
            uint4 wC = *(const uint4*)(wp + 8);
            uint4 wD = *(const uint4*)(wp + 12);
            unsigned int hh[16] = {hA.x, hA.y, hA.z, hA.w, hB.x, hB.y, hB.z, hB.w,
                                   hC.x, hC.y, hC.z, hC.w, hD.x, hD.y, hD.z, hD.w};
            unsigned int ww[16] = {wA.x, wA.y, wA.z, wA.w, wB.x, wB.y, wB.z, wB.w,
                                   wC.x, wC.y, wC.z, wC.w, wD.x, wD.y, wD.z, wD.w};

            float acc = 0.f;
            #pragma unroll
            for (int j = 0; j < 16; ++j)
                acc = __builtin_amdgcn_fdot2(__builtin_bit_cast(half2v, ww[j]),
                                             __builtin_bit_cast(half2v, hh[j]),
                                             acc, false);
            acc = dpp_radd<SHL4>(acc);
            acc = dpp_radd<SHL2>(acc);
            acc = dpp_radd<SHL1>(acc);

            if (sub == 0) {
                out[((size_t)(chunk * CHUNK + s) * BATCH + b) * OUTD + o] =
                    fast_tanh(acc + (o ? bf1 : bf0));
            }
            __syncthreads();  // protect ring before next chunk overwrites
        }
    }
}

extern "C" void kernel_launch(void* const* d_in, const int* in_sizes, int n_in,
                              void* d_out, int out_size, void* d_ws, size_t ws_size,
                              hipStream_t stream) {
    const float* input = (const float*)d_in[0];
    // d_in[1] = target (unused by forward)
    const float* Wi = (const float*)d_in[2];
    const float* bi = (const float*)d_in[3];
    const float* Wh = (const float*)d_in[4];
    const float* bh = (const float*)d_in[5];
    const float* Wf = (const float*)d_in[6];
    const float* bf = (const float*)d_in[7];
    float* out = (float*)d_out;

    elman_kernel<<<dim3(BATCH), dim3(512), 0, stream>>>(
        input, Wi, bi, Wh, bh, Wf, bf, out);
}

// Round 10
// 2361.152 us; speedup vs baseline: 1.1734x; 1.1734x over previous
//
#include <hip/hip_runtime.h>

#define T_STEPS 4096
#define BATCH   64
#define INDIM   4
#define H       256
#define OUTD    2
#define CHUNK   32
#define SLOT_DW 36                    // dwords per k-quarter: 32 + 4 skew
#define ENT_DW  (4*SLOT_DW)           // 144 dwords per stored h vector
#define ENT_B   (4*ENT_DW)            // 576 bytes
#define RING_DW (CHUNK*ENT_DW)        // 4608 dwords (18 KB)
#define DUMP_DW 256                   // 1 KB dump for non-writer lanes

typedef __fp16 half2v __attribute__((ext_vector_type(2)));

__device__ __forceinline__ float fast_tanh(float x) {
    float ax = fabsf(x);
    float e  = __expf(-2.0f * ax);
    float r  = (1.0f - e) * __builtin_amdgcn_rcpf(1.0f + e);
    return copysignf(r, x);
}

template<int CTRL>
__device__ __forceinline__ float dpp_radd(float a) {
    int s = __builtin_amdgcn_update_dpp(0, __builtin_bit_cast(int, a),
                                        CTRL, 0xf, 0xf, true);
    return a + __builtin_bit_cast(float, s);
}
#define SHL1 0x101
#define SHL2 0x102
#define SHR1 0x111
#define SHR2 0x112

// R8 structure (best known: 2294 us), MAC engine swapped to v_pk_fma_f16.
// R9 post-mortem: dot2 appears to issue at ~4cyc/wave (half rate) — pk_fma
// at full rate doubles MAC throughput. f16 accumulation over 8-term
// sub-chains, folded to f32 via one fdot2((1,1)) each.
__global__ __attribute__((amdgpu_waves_per_eu(2, 2))) __launch_bounds__(512)
void elman_kernel(const float* __restrict__ input,
                  const float* __restrict__ Wi,
                  const float* __restrict__ bi,
                  const float* __restrict__ Wh,
                  const float* __restrict__ bh,
                  const float* __restrict__ Wf,
                  const float* __restrict__ bf,
                  float* __restrict__ out)
{
    const int b  = blockIdx.x;
    const int t  = threadIdx.x;
    const int rp = t >> 2;        // row pair 0..127
    const int ko = t & 3;         // k-quarter
    const int r0 = rp * 2, r1 = r0 + 1;
    const int k0 = ko * 64;

    __shared__ unsigned int lds[RING_DW + DUMP_DW + OUTD * (H / 2)];
    unsigned int* ring  = lds;
    unsigned int* wf_pk = lds + RING_DW + DUMP_DW;

    // --- weights: 2 rows x 64 k packed f16 -> 64 dwords ---
    half2v w0[32], w1[32];
    {
        const float* p0 = Wh + (size_t)r0 * H + k0;
        const float* p1 = Wh + (size_t)r1 * H + k0;
        #pragma unroll
        for (int j = 0; j < 16; ++j) {
            float4 a = *(const float4*)(p0 + 4 * j);
            float4 c = *(const float4*)(p1 + 4 * j);
            w0[2 * j]     = __builtin_amdgcn_cvt_pkrtz(a.x, a.y);
            w0[2 * j + 1] = __builtin_amdgcn_cvt_pkrtz(a.z, a.w);
            w1[2 * j]     = __builtin_amdgcn_cvt_pkrtz(c.x, c.y);
            w1[2 * j + 1] = __builtin_amdgcn_cvt_pkrtz(c.z, c.w);
        }
    }
    #pragma unroll
    for (int j = 0; j < 32; ++j) {
        float f0 = __builtin_bit_cast(float, w0[j]);
        float f1 = __builtin_bit_cast(float, w1[j]);
        asm volatile("" : "+v"(f0), "+v"(f1));
        w0[j] = __builtin_bit_cast(half2v, f0);
        w1[j] = __builtin_bit_cast(half2v, f1);
    }

    // epilogue role: lane ko==0 finalizes row r0, lane ko==3 finalizes row r1
    const int  ko3      = (ko == 3);
    const int  row_mine = r0 + ko3;
    const int  is_wr    = (ko == 0) | ko3;
    const float4 wim    = *(const float4*)(Wi + row_mine * INDIM);
    const float  biasm  = bi[row_mine] + bh[row_mine];
    const float  bf0    = bf[0], bf1 = bf[1];
    const int  boff     = (row_mine >> 6) * (SLOT_DW * 4) + (row_mine & 63) * 2;
    const int  dumpoff  = RING_DW * 4 + t * 2;

    if (t < OUTD * (H / 2)) {
        const int o = t >> 7, e = t & 127;
        wf_pk[t] = __builtin_bit_cast(unsigned int,
            __builtin_amdgcn_cvt_pkrtz(Wf[o * H + 2 * e], Wf[o * H + 2 * e + 1]));
    }
    if (t < H / 2) ring[(CHUNK - 1) * ENT_DW + (t >> 5) * SLOT_DW + (t & 31)] = 0u;
    __syncthreads();

    float4 xcur = *(const float4*)(input + (size_t)b * INDIM);  // step 0
    const unsigned int rd_off = (unsigned int)(ko * SLOT_DW);
    const half2v one11 = {(__fp16)1.0f, (__fp16)1.0f};

    for (int chunk = 0; chunk < T_STEPS / CHUNK; ++chunk) {
        #pragma unroll 1
        for (int i = 0; i < CHUNK; ++i) {
            const int step = chunk * CHUNK + i;
            int s2 = step + 1; if (s2 >= T_STEPS) s2 = T_STEPS - 1;
            float4 xnext = *(const float4*)(input + ((size_t)s2 * BATCH + b) * INDIM);

            const unsigned int* hb =
                ring + ((i + CHUNK - 1) & (CHUNK - 1)) * ENT_DW + rd_off;
            uint4 hv[8];
            #pragma unroll
            for (int j = 0; j < 8; ++j) hv[j] = *(const uint4*)(hb + 4 * j);

            // 8 f16 sub-chains (4 per row, 8 pk_fma each), folded to f32
            half2v s0a = {0, 0}, s0b = {0, 0}, s0c = {0, 0}, s0d = {0, 0};
            half2v s1a = {0, 0}, s1b = {0, 0}, s1c = {0, 0}, s1d = {0, 0};
            {
                #pragma clang fp contract(fast)
                #pragma unroll
                for (int j = 0; j < 2; ++j) {
                    half2v h0 = __builtin_bit_cast(half2v, hv[j].x);
                    half2v h1 = __builtin_bit_cast(half2v, hv[j].y);
                    half2v h2 = __builtin_bit_cast(half2v, hv[j].z);
                    half2v h3 = __builtin_bit_cast(half2v, hv[j].w);
                    s0a = s0a + w0[4 * j] * h0;     s1a = s1a + w1[4 * j] * h0;
                    s0a = s0a + w0[4 * j + 1] * h1; s1a = s1a + w1[4 * j + 1] * h1;
                    s0a = s0a + w0[4 * j + 2] * h2; s1a = s1a + w1[4 * j + 2] * h2;
                    s0a = s0a + w0[4 * j + 3] * h3; s1a = s1a + w1[4 * j + 3] * h3;
                }
                #pragma unroll
                for (int j = 2; j < 4; ++j) {
                    half2v h0 = __builtin_bit_cast(half2v, hv[j].x);
                    half2v h1 = __builtin_bit_cast(half2v, hv[j].y);
                    half2v h2 = __builtin_bit_cast(half2v, hv[j].z);
                    half2v h3 = __builtin_bit_cast(half2v, hv[j].w);
                    s0b = s0b + w0[4 * j] * h0;     s1b = s1b + w1[4 * j] * h0;
                    s0b = s0b + w0[4 * j + 1] * h1; s1b = s1b + w1[4 * j + 1] * h1;
                    s0b = s0b + w0[4 * j + 2] * h2; s1b = s1b + w1[4 * j + 2] * h2;
                    s0b = s0b + w0[4 * j + 3] * h3; s1b = s1b + w1[4 * j + 3] * h3;
                }
                #pragma unroll
                for (int j = 4; j < 6; ++j) {
                    half2v h0 = __builtin_bit_cast(half2v, hv[j].x);
                    half2v h1 = __builtin_bit_cast(half2v, hv[j].y);
                    half2v h2 = __builtin_bit_cast(half2v, hv[j].z);
                    half2v h3 = __builtin_bit_cast(half2v, hv[j].w);
                    s0c = s0c + w0[4 * j] * h0;     s1c = s1c + w1[4 * j] * h0;
                    s0c = s0c + w0[4 * j + 1] * h1; s1c = s1c + w1[4 * j + 1] * h1;
                    s0c = s0c + w0[4 * j + 2] * h2; s1c = s1c + w1[4 * j + 2] * h2;
                    s0c = s0c + w0[4 * j + 3] * h3; s1c = s1c + w1[4 * j + 3] * h3;
                }
                #pragma unroll
                for (int j = 6; j < 8; ++j) {
                    half2v h0 = __builtin_bit_cast(half2v, hv[j].x);
                    half2v h1 = __builtin_bit_cast(half2v, hv[j].y);
                    half2v h2 = __builtin_bit_cast(half2v, hv[j].z);
                    half2v h3 = __builtin_bit_cast(half2v, hv[j].w);
                    s0d = s0d + w0[4 * j] * h0;     s1d = s1d + w1[4 * j] * h0;
                    s0d = s0d + w0[4 * j + 1] * h1; s1d = s1d + w1[4 * j + 1] * h1;
                    s0d = s0d + w0[4 * j + 2] * h2; s1d = s1d + w1[4 * j + 2] * h2;
                    s0d = s0d + w0[4 * j + 3] * h3; s1d = s1d + w1[4 * j + 3] * h3;
                }
            }
            float acc0 = 0.f, acc1 = 0.f;
            acc0 = __builtin_amdgcn_fdot2(s0a, one11, acc0, false);
            acc0 = __builtin_amdgcn_fdot2(s0b, one11, acc0, false);
            acc0 = __builtin_amdgcn_fdot2(s0c, one11, acc0, false);
            acc0 = __builtin_amdgcn_fdot2(s0d, one11, acc0, false);
            acc1 = __builtin_amdgcn_fdot2(s1a, one11, acc1, false);
            acc1 = __builtin_amdgcn_fdot2(s1b, one11, acc1, false);
            acc1 = __builtin_amdgcn_fdot2(s1c, one11, acc1, false);
            acc1 = __builtin_amdgcn_fdot2(s1d, one11, acc1, false);

            // DPP reduce over the 4-lane group: acc0 -> lane 0, acc1 -> lane 3
            acc0 = dpp_radd<SHL2>(acc0);
            acc0 = dpp_radd<SHL1>(acc0);
            acc1 = dpp_radd<SHR2>(acc1);
            acc1 = dpp_radd<SHR1>(acc1);

            // unmasked epilogue: every lane finalizes one row (2 of 4 valid)
            float accm = ko3 ? acc1 : acc0;
            float pre  = accm + biasm +
                xcur.x * wim.x + xcur.y * wim.y + xcur.z * wim.z + xcur.w * wim.w;
            __fp16 h16 = (__fp16)fast_tanh(pre);
            int waddr  = is_wr ? (i * ENT_B + boff) : dumpoff;
            *(__fp16*)((char*)lds + waddr) = h16;

            xcur = xnext;
            __syncthreads();
        }

        // --- deferred output head: 64 tasks x 8 lanes ---
        {
            const int task = t >> 3;
            const int s    = task >> 1;
            const int o    = task & 1;
            const int sub  = t & 7;
            const unsigned int* hp =
                ring + s * ENT_DW + (sub >> 1) * SLOT_DW + (sub & 1) * 16;
            const unsigned int* wp = wf_pk + o * (H / 2) + sub * 16;

            uint4 hA = *(const uint4*)(hp);
            uint4 hB = *(const uint4*)(hp + 4);
            uint4 hC = *(const uint4*)(hp + 8);
            uint4 hD = *(const uint4*)(hp + 12);
            uint4 wA = *(const uint4*)(wp);
            uint4 wB = *(const uint4*)(wp + 4);
            uint4 wC = *(const uint4*)(wp + 8);
            uint4 wD = *(const uint4*)(wp + 12);
            unsigned int hh[16] = {hA.x, hA.y, hA.z, hA.w, hB.x, hB.y, hB.z, hB.w,
                                   hC.x, hC.y, hC.z, hC.w, hD.x, hD.y, hD.z, hD.w};
            unsigned int ww[16] = {wA.x, wA.y, wA.z, wA.w, wB.x, wB.y, wB.z, wB.w,
                                   wC.x, wC.y, wC.z, wC.w, wD.x, wD.y, wD.z, wD.w};

            float acc = 0.f;
            #pragma unroll
            for (int j = 0; j < 16; ++j)
                acc = __builtin_amdgcn_fdot2(__builtin_bit_cast(half2v, ww[j]),
                                             __builtin_bit_cast(half2v, hh[j]),
                                             acc, false);
            acc = dpp_radd<0x104>(acc);
            acc = dpp_radd<SHL2>(acc);
            acc = dpp_radd<SHL1>(acc);

            if (sub == 0) {
                out[((size_t)(chunk * CHUNK + s) * BATCH + b) * OUTD + o] =
                    fast_tanh(acc + (o ? bf1 : bf0));
            }
            __syncthreads();
        }
    }
}

extern "C" void kernel_launch(void* const* d_in, const int* in_sizes, int n_in,
                              void* d_out, int out_size, void* d_ws, size_t ws_size,
                              hipStream_t stream) {
    const float* input = (const float*)d_in[0];
    // d_in[1] = target (unused by forward)
    const float* Wi = (const float*)d_in[2];
    const float* bi = (const float*)d_in[3];
    const float* Wh = (const float*)d_in[4];
    const float* bh = (const float*)d_in[5];
    const float* Wf = (const float*)d_in[6];
    const float* bf = (const float*)d_in[7];
    float* out = (float*)d_out;

    elman_kernel<<<dim3(BATCH), dim3(512), 0, stream>>>(
        input, Wi, bi, Wh, bh, Wf, bf, out);
}